// Round 7
// baseline (686.664 us; speedup 1.0000x reference)
//
#include <hip/hip_runtime.h>
#include <hip/hip_bf16.h>
#include <stdint.h>

#define B_ 256
#define S_ 256
#define D_ 1024
#define P_ 512
#define SH 254            /* S-2 */
#define M_ (B_*SH)        /* 65024 */
#define EPSF 1e-7f
#define APITCH 1032       /* shorts: 1024 + 8 pad; 516 dwords = 4 mod 32 */

typedef __attribute__((ext_vector_type(8))) short short8v;
typedef __attribute__((ext_vector_type(4))) short short4v;
typedef __attribute__((ext_vector_type(4))) float float4v;

__device__ inline short f2bf(float f) {
  __hip_bfloat16 h = __float2bfloat16(f);
  return *reinterpret_cast<short*>(&h);
}
__device__ inline float fast_tanh(float x) {
  float e = __expf(2.0f * x);
  return 1.0f - 2.0f * __builtin_amdgcn_rcpf(e + 1.0f);
}

// ---------------- mask dtype detection ----------------
__global__ void k_detect(const unsigned char* m, int* flag) {
  __shared__ int c0, c3;
  if (threadIdx.x == 0) { c0 = 0; c3 = 0; }
  __syncthreads();
  int f0 = 0, f3 = 0;
  for (int i = threadIdx.x; i < 4096; i += 256) {
    unsigned char v = m[i];
    if (v != 0) {
      if ((i & 3) == 0) f0 = 1;
      if ((i & 3) == 3) f3 = 1;
    }
  }
  if (f0) atomicOr(&c0, 1);
  if (f3) atomicOr(&c3, 1);
  __syncthreads();
  if (threadIdx.x == 0) {
    int f;
    if (c3 == 0) f = 0;
    else if (c0 != 0) f = 1;
    else f = 2;
    *flag = f;
  }
}

// proj_head (D x P) -> chunked transposed bf16: out[kc*(P*32) + n*32 + kr]
__global__ void k_trans_head(const float* __restrict__ w, short* __restrict__ out) {
  int idx = blockIdx.x * 256 + threadIdx.x;   // 262144 threads
  int kc  = idx >> 13;
  int j   = idx & 8191;
  int krp = j >> 9;
  int n   = j & 511;
  int k0  = kc * 32 + krp * 2;
  unsigned lo = (unsigned short)f2bf(w[(size_t)k0 * P_ + n]);
  unsigned hi = (unsigned short)f2bf(w[(size_t)(k0 + 1) * P_ + n]);
  ((unsigned*)out)[kc * 8192 + n * 16 + krp] = lo | (hi << 16);
}

// hidden (2 x P x P) -> two chunked transposed bf16 arrays
__global__ void k_trans_hidden(const float* __restrict__ h,
                               short* __restrict__ o0, short* __restrict__ o1) {
  int idx = blockIdx.x * 256 + threadIdx.x;   // 262144 threads
  int which = idx >> 17;
  int j = idx & 131071;
  int kc  = j >> 13;
  int r   = j & 8191;
  int krp = r >> 9;
  int n   = r & 511;
  const float* hs = h + (size_t)which * (P_*P_);
  int k0 = kc * 32 + krp * 2;
  unsigned lo = (unsigned short)f2bf(hs[(size_t)k0 * P_ + n]);
  unsigned hi = (unsigned short)f2bf(hs[(size_t)(k0 + 1) * P_ + n]);
  unsigned* o = (unsigned*)(which ? o1 : o0);
  o[kc * 8192 + n * 16 + krp] = lo | (hi << 16);
}

// pc[b][p] = x[b,254,:]@proj_prep[:,p] + x[b,255,:]@proj_child[:,p]
__global__ void __launch_bounds__(512) k_pc(const float* __restrict__ x,
                                            const float* __restrict__ wp,
                                            const float* __restrict__ wc,
                                            float* __restrict__ pc) {
  __shared__ float xs[16][256];
  int bg = blockIdx.x >> 4, cs = blockIdx.x & 15;
  int t = threadIdx.x;
  int bloc = t >> 5, c = t & 31;
  int batch = bg * 16 + bloc;
  int col = cs * 32 + c;
  float acc = 0.f;
  #pragma unroll
  for (int half = 0; half < 2; half++) {
    const float* wsrc = half ? wc : wp;
    for (int kc = 0; kc < 4; kc++) {
      const float* xr = x + ((size_t)(batch * S_ + SH + half)) * D_ + kc*256 + c*8;
      float4 v0 = *(const float4*)(xr + 0);
      float4 v1 = *(const float4*)(xr + 4);
      __syncthreads();
      *(float4*)&xs[bloc][c*8 + 0] = v0;
      *(float4*)&xs[bloc][c*8 + 4] = v1;
      __syncthreads();
      const float* wv = wsrc + (size_t)(kc*256) * P_ + col;
      #pragma unroll 8
      for (int d = 0; d < 256; d++) {
        acc += xs[bloc][d] * wv[(size_t)d * P_];
      }
    }
  }
  pc[batch * P_ + col] = acc;
}

// ---------------- fused 3-GEMM main kernel ----------------
// 1024 threads = 16 waves (4/SIMD), tile 64 rows x 512 cols; wave = 64r x 32c
// (acc[4][2] = 32 AGPR). A-tile (64x1024 bf16, 132 KB) staged to LDS ONCE
// (coalesced, interleaved), then stage-1 K-loop runs with ZERO barriers so
// waves de-phase and L2/LDS/MFMA bursts interleave. B direct from L2 weights
// with register prefetch distance 2. Cs (composed) aliases the A buffer.
__global__ void __launch_bounds__(1024, 4) k_main(
    const float* __restrict__ x, const short* __restrict__ wth,
    const short* __restrict__ h0t, const short* __restrict__ h1t,
    const float* __restrict__ scorer, const float* __restrict__ pc,
    float* __restrict__ scores)
{
  __shared__ __attribute__((aligned(16))) short Abuf[64*APITCH];  // 132096 B
  __shared__ float scorer_s[P_];
  __shared__ float pcs[2][P_];
  __shared__ float score_ws[64][16];

  short* Cs = Abuf;   // alias: stage 1 fully consumes Abuf before Cs written

  const int tid  = threadIdx.x;
  const int lane = tid & 63;
  const int w    = tid >> 6;            // 0..15, column strip w*32
  const int l15  = lane & 15, quad = lane >> 4;
  const int rowbase = blockIdx.x * 64;

  const int bb0 = rowbase / SH;
  const int bb1 = (rowbase + 63) / SH;
  if (tid < P_) {
    scorer_s[tid] = scorer[tid];
    pcs[0][tid] = pc[bb0 * P_ + tid];
    pcs[1][tid] = pc[bb1 * P_ + tid];
  }
  const int lim1 = (bb0 + 1) * SH;

  const int bcol = (w*32 + l15)*4 + quad;   // uint4 index; nt=1 -> +64
  const uint4* wbv = (const uint4*)wth;
  const uint4* h0v = (const uint4*)h0t;
  const uint4* h1v = (const uint4*)h1t;

  // ---- one-shot A staging: 64 rows x 1024 k, fp32 -> bf16 ----
  // 16 threads per row; interleaved so each instruction is a 256 B segment.
  {
    const int srow = tid >> 4;          // 0..63
    const int sk   = tid & 15;
    int r0 = rowbase + srow;
    int ab = r0 / SH;
    int as_ = r0 - ab * SH;
    const float* rp = x + ((size_t)(ab * S_ + as_)) * D_;
    #pragma unroll
    for (int i = 0; i < 16; i++) {
      int k0 = (i*16 + sk) * 4;         // 4 consecutive floats
      float4 v = *(const float4*)(rp + k0);
      short4v s = { f2bf(v.x), f2bf(v.y), f2bf(v.z), f2bf(v.w) };
      *(short4v*)&Abuf[srow*APITCH + k0] = s;
    }
  }

  float4v acc[4][2];
  #pragma unroll
  for (int i = 0; i < 4; i++) { acc[i][0] = (float4v){0.f,0.f,0.f,0.f};
                                acc[i][1] = (float4v){0.f,0.f,0.f,0.f}; }

  // preload B kc=0,1 (depth-2 prefetch)
  uint4 b[2][2];
  b[0][0] = wbv[bcol];        b[0][1] = wbv[bcol + 64];
  b[1][0] = wbv[2048 + bcol]; b[1][1] = wbv[2048 + bcol + 64];
  __syncthreads();   // A-tile ready

  // ---- Stage 1: K=1024, 32 chunks, NO barriers ----
  for (int kc = 0; kc < 32; kc++) {
    const int s = kc & 1;
    uint4 c0 = b[s][0], c1 = b[s][1];
    if (kc < 30) {
      b[s][0] = wbv[(size_t)(kc+2)*2048 + bcol];
      b[s][1] = wbv[(size_t)(kc+2)*2048 + bcol + 64];
    } else if (kc == 30) {            // cross prefetch: h0 kc=0
      b[s][0] = h0v[bcol];
      b[s][1] = h0v[bcol + 64];
    } else {                          // kc==31: h0 kc=1
      b[s][0] = h0v[2048 + bcol];
      b[s][1] = h0v[2048 + bcol + 64];
    }
    #pragma unroll
    for (int mt = 0; mt < 4; mt++) {
      short8v a = *(const short8v*)&Abuf[(mt*16 + l15)*APITCH + kc*32 + quad*8];
      acc[mt][0] = __builtin_amdgcn_mfma_f32_16x16x32_bf16(a, *(short8v*)&c0, acc[mt][0], 0, 0, 0);
      acc[mt][1] = __builtin_amdgcn_mfma_f32_16x16x32_bf16(a, *(short8v*)&c1, acc[mt][1], 0, 0, 0);
    }
  }
  __syncthreads();   // all stage-1 A reads done; Cs may overwrite Abuf

  // epilogue 1: + pc bias, tanh -> Cs
  #pragma unroll
  for (int mt = 0; mt < 4; mt++) {
    #pragma unroll
    for (int j = 0; j < 4; j++) {
      int rl = mt*16 + quad*4 + j;
      int rg = rowbase + rl;
      const float* pcb = (rg >= lim1) ? pcs[1] : pcs[0];
      #pragma unroll
      for (int nt = 0; nt < 2; nt++) {
        int col = w*32 + nt*16 + l15;
        float v = fast_tanh(acc[mt][nt][j] + pcb[col]);
        float o = __shfl_xor(v, 1, 64);
        unsigned hs = (unsigned short)f2bf(v);
        unsigned ho = (unsigned short)f2bf(o);
        if ((l15 & 1) == 0)
          *(unsigned*)&Cs[rl*520 + col] = hs | (ho << 16);
      }
    }
  }
  __syncthreads();

  // ---- Stages 2 & 3: K=512, A from Cs, B depth-2 reg prefetch ----
  #pragma unroll 1
  for (int stage = 0; stage < 2; stage++) {
    const uint4* hb = stage ? h1v : h0v;
    #pragma unroll
    for (int i = 0; i < 4; i++) { acc[i][0] = (float4v){0.f,0.f,0.f,0.f};
                                  acc[i][1] = (float4v){0.f,0.f,0.f,0.f}; }
    for (int kc = 0; kc < 16; kc++) {
      const int s = kc & 1;
      uint4 c0 = b[s][0], c1 = b[s][1];
      if (kc < 14) {
        b[s][0] = hb[(size_t)(kc+2)*2048 + bcol];
        b[s][1] = hb[(size_t)(kc+2)*2048 + bcol + 64];
      } else if (stage == 0) {        // cross prefetch h1 kc=0,1
        b[s][0] = h1v[(size_t)(kc-14)*2048 + bcol];
        b[s][1] = h1v[(size_t)(kc-14)*2048 + bcol + 64];
      }
      #pragma unroll
      for (int mt = 0; mt < 4; mt++) {
        short8v a = *(const short8v*)&Cs[(mt*16 + l15)*520 + kc*32 + quad*8];
        acc[mt][0] = __builtin_amdgcn_mfma_f32_16x16x32_bf16(a, *(short8v*)&c0, acc[mt][0], 0, 0, 0);
        acc[mt][1] = __builtin_amdgcn_mfma_f32_16x16x32_bf16(a, *(short8v*)&c1, acc[mt][1], 0, 0, 0);
      }
    }

    if (stage == 0) {
      __syncthreads();   // all Cs reads done before overwrite
      #pragma unroll
      for (int mt = 0; mt < 4; mt++) {
        #pragma unroll
        for (int j = 0; j < 4; j++) {
          int rl = mt*16 + quad*4 + j;
          #pragma unroll
          for (int nt = 0; nt < 2; nt++) {
            int col = w*32 + nt*16 + l15;
            float v = fast_tanh(acc[mt][nt][j]);
            float o = __shfl_xor(v, 1, 64);
            unsigned hs = (unsigned short)f2bf(v);
            unsigned ho = (unsigned short)f2bf(o);
            if ((l15 & 1) == 0)
              *(unsigned*)&Cs[rl*520 + col] = hs | (ho << 16);
          }
        }
      }
      __syncthreads();
    }
  }

  // ---- epilogue 3: tanh, scorer dot, reduce ----
  #pragma unroll
  for (int mt = 0; mt < 4; mt++) {
    #pragma unroll
    for (int j = 0; j < 4; j++) {
      int rl = mt*16 + quad*4 + j;
      float part = fast_tanh(acc[mt][0][j]) * scorer_s[w*32 + l15]
                 + fast_tanh(acc[mt][1][j]) * scorer_s[w*32 + 16 + l15];
      #pragma unroll
      for (int o = 1; o < 16; o <<= 1) part += __shfl_xor(part, o, 64);
      if (l15 == 0) score_ws[rl][w] = part;
    }
  }
  __syncthreads();
  if (tid < 64) {
    float s = 0.f;
    #pragma unroll
    for (int k = 0; k < 16; k++) s += score_ws[tid][k];
    scores[rowbase + tid] = __expf(s);
  }
}

// ---------------- masked softmax ----------------
__global__ void __launch_bounds__(256) k_softmax(const float* __restrict__ scores,
                                                 const void* __restrict__ mask,
                                                 const int* __restrict__ flag,
                                                 float* __restrict__ out) {
  int b = blockIdx.x, t = threadIdx.x;
  int lane = t & 63, w = t >> 6;
  __shared__ float ps[4];
  float me = 0.f;
  bool valid = t < SH;
  if (valid) {
    float e = scores[b*SH + t];
    int f = *flag;
    bool mb;
    if (f == 1)      mb = ((const unsigned char*)mask)[b*S_ + t] != 0;
    else if (f == 2) mb = ((const float*)mask)[b*S_ + t] != 0.0f;
    else             mb = ((const int*)mask)[b*S_ + t] != 0;
    me = mb ? e : 0.f;
  }
  float v = me;
  for (int o = 1; o < 64; o <<= 1) v += __shfl_xor(v, o, 64);
  if (lane == 0) ps[w] = v;
  __syncthreads();
  float tot = ps[0] + ps[1] + ps[2] + ps[3] + EPSF;
  if (valid) out[b*SH + t] = me / tot;
}

extern "C" void kernel_launch(void* const* d_in, const int* in_sizes, int n_in,
                              void* d_out, int out_size, void* d_ws, size_t ws_size,
                              hipStream_t stream) {
  const float* x          = (const float*)d_in[0];
  const float* proj_head  = (const float*)d_in[1];
  const float* proj_prep  = (const float*)d_in[2];
  const float* proj_child = (const float*)d_in[3];
  const float* hidden     = (const float*)d_in[4];
  const float* scorer     = (const float*)d_in[5];
  const void*  mask       = d_in[6];
  float* out = (float*)d_out;
  char* ws = (char*)d_ws;

  int*   flag   = (int*)  (ws + 0);
  float* pc     = (float*)(ws + 256);
  short* wth    = (short*)(ws + 524544);
  short* h0t    = (short*)(ws + 1573120);
  short* h1t    = (short*)(ws + 2097408);
  float* scores = (float*)(ws + 2621696);

  k_detect<<<1, 256, 0, stream>>>((const unsigned char*)mask, flag);
  k_trans_head<<<1024, 256, 0, stream>>>(proj_head, wth);
  k_trans_hidden<<<1024, 256, 0, stream>>>(hidden, h0t, h1t);
  k_pc<<<256, 512, 0, stream>>>(x, proj_prep, proj_child, pc);
  k_main<<<1016, 1024, 0, stream>>>(x, wth, h0t, h1t, scorer, pc, scores);
  k_softmax<<<256, 256, 0, stream>>>(scores, mask, flag, out);
}